// Round 4
// baseline (2408.289 us; speedup 1.0000x reference)
//
#include <hip/hip_runtime.h>
#include <hip/hip_bf16.h>
#include <cmath>

// Problem constants. I/O is FP32 (per reference); internals bf16 (threshold
// floor_eps_k=8 permits bf16 tensor-core compute).
#define B_ 4
#define S_ 2048
#define DM_ 1024
#define H_ 16
#define DH_ 64
#define BS_ (B_*S_)   // 8192 rows

typedef __bf16 bf16x8 __attribute__((ext_vector_type(8)));
typedef float  floatx4 __attribute__((ext_vector_type(4)));

// ---------------------------------------------------------------------------
// Batched 32x32 transpose: fp32 src[R][C] -> bf16 dst[C][R] (per batch)
// ---------------------------------------------------------------------------
__global__ void transpose_kernel(const float* __restrict__ src, __bf16* __restrict__ dst,
                                 int R, int C, long srcBatch, long dstBatch) {
  __shared__ __bf16 tile[32][33];
  int b = blockIdx.z;
  long sb = (long)b * srcBatch;
  dst += (long)b * dstBatch;
  int c0 = blockIdx.x * 32, r0 = blockIdx.y * 32;
  int tx = threadIdx.x, ty = threadIdx.y;      // block (32, 8)
  #pragma unroll
  for (int i = 0; i < 32; i += 8)
    tile[ty + i][tx] = (__bf16)src[sb + (long)(r0 + ty + i) * C + (c0 + tx)];
  __syncthreads();
  #pragma unroll
  for (int i = 0; i < 32; i += 8)
    dst[(long)(c0 + ty + i) * R + (r0 + tx)] = tile[tx][ty + i];
}

// ---------------------------------------------------------------------------
// Tiled MFMA GEMM: C[M][N] = A[M][K] * B[K][N], B supplied TRANSPOSED
// (bf16 Bt[N][K]). BM=BN=128, BK=64. 256 threads = 4 waves, wave = 64x64.
// EPI==0: A is FP32 (x), epilogue -> Q(*0.125)/K/V bf16 [B,H,S,64], fp32 bias
// EPI==1: A is bf16 (vout), epilogue -> fp32 out[M][N] + fp32 bias
// ---------------------------------------------------------------------------
#define BM 128
#define BN 128
#define BK 64
#define LDK 72   // padded LDS row stride (elements)

template<int EPI>
__global__ __launch_bounds__(256, 2) void gemm_kernel(
    const void* __restrict__ Avoid, const __bf16* __restrict__ Bt,
    int M, int N, int K,
    const float* __restrict__ bq, const float* __restrict__ bk,
    const float* __restrict__ bv, const float* __restrict__ bo,
    __bf16* __restrict__ q_ws, __bf16* __restrict__ k_ws,
    __bf16* __restrict__ v_ws, float* __restrict__ out) {

  __shared__ __align__(16) __bf16 As[BM * LDK];
  __shared__ __align__(16) __bf16 Bs[BN * LDK];

  int tid  = threadIdx.x;
  int wave = tid >> 6, lane = tid & 63;
  int quad = lane >> 4, l15 = lane & 15;
  int wm = (wave >> 1) * 64, wn = (wave & 1) * 64;
  long m0 = (long)blockIdx.y * BM;
  long n0 = (long)blockIdx.x * BN;

  floatx4 acc[4][4] = {};   // [mt][nt]

  int arow  = tid >> 1;              // 0..127
  int ahalf = (tid & 1) * 32;        // element offset 0 or 32
  const float*  Af = (const float*) Avoid;   // EPI==0
  const __bf16* Ab = (const __bf16*)Avoid;   // EPI==1
  const __bf16* Bptr = Bt + (n0 + arow) * (long)K + ahalf;

  for (int k0 = 0; k0 < K; k0 += BK) {
    bf16x8 avb[4], bvv[4];
    if (EPI == 0) {
      const float* Ap = Af + (m0 + arow) * (long)K + ahalf + k0;
      #pragma unroll
      for (int c = 0; c < 4; c++) {
        float4 lo = *(const float4*)(Ap + c * 8);
        float4 hi = *(const float4*)(Ap + c * 8 + 4);
        bf16x8 t;
        t[0] = (__bf16)lo.x; t[1] = (__bf16)lo.y; t[2] = (__bf16)lo.z; t[3] = (__bf16)lo.w;
        t[4] = (__bf16)hi.x; t[5] = (__bf16)hi.y; t[6] = (__bf16)hi.z; t[7] = (__bf16)hi.w;
        avb[c] = t;
      }
    } else {
      const __bf16* Ap = Ab + (m0 + arow) * (long)K + ahalf + k0;
      #pragma unroll
      for (int c = 0; c < 4; c++) avb[c] = *(const bf16x8*)(Ap + c * 8);
    }
    #pragma unroll
    for (int c = 0; c < 4; c++) bvv[c] = *(const bf16x8*)(Bptr + k0 + c * 8);

    __syncthreads();   // WAR: previous iter's fragment reads done before overwrite
    #pragma unroll
    for (int c = 0; c < 4; c++) *(bf16x8*)(&As[arow * LDK + ahalf + c * 8]) = avb[c];
    #pragma unroll
    for (int c = 0; c < 4; c++) *(bf16x8*)(&Bs[arow * LDK + ahalf + c * 8]) = bvv[c];
    __syncthreads();

    #pragma unroll
    for (int kk = 0; kk < 2; kk++) {
      bf16x8 af[4], bff[4];
      #pragma unroll
      for (int mt = 0; mt < 4; mt++)
        af[mt] = *(const bf16x8*)(&As[(wm + mt * 16 + l15) * LDK + kk * 32 + quad * 8]);
      #pragma unroll
      for (int nt = 0; nt < 4; nt++)
        bff[nt] = *(const bf16x8*)(&Bs[(wn + nt * 16 + l15) * LDK + kk * 32 + quad * 8]);
      #pragma unroll
      for (int mt = 0; mt < 4; mt++)
        #pragma unroll
        for (int nt = 0; nt < 4; nt++)
          acc[mt][nt] = __builtin_amdgcn_mfma_f32_16x16x32_bf16(af[mt], bff[nt], acc[mt][nt], 0, 0, 0);
    }
  }

  if (EPI == 0) {
    // n in [0,3072): seg 0=Q,1=K,2=V ; h=(n&1023)>>6 ; e=n&63
    #pragma unroll
    for (int nt = 0; nt < 4; nt++) {
      long n = n0 + wn + nt * 16 + l15;
      int seg = (int)(n >> 10);
      int he  = (int)(n & 1023);
      int h = he >> 6, e = he & 63;
      const float* bias = (seg == 0 ? bq : (seg == 1 ? bk : bv));
      float bval = bias[he];
      __bf16* dst = (seg == 0 ? q_ws : (seg == 1 ? k_ws : v_ws));
      float scale = (seg == 0 ? 0.125f : 1.0f);   // fold 1/sqrt(64) into Q
      #pragma unroll
      for (int mt = 0; mt < 4; mt++) {
        #pragma unroll
        for (int r = 0; r < 4; r++) {
          long m = m0 + wm + mt * 16 + quad * 4 + r;
          int b = (int)(m >> 11), s = (int)(m & 2047);
          float v = (acc[mt][nt][r] + bval) * scale;
          dst[((long)(b * 16 + h) * 2048 + s) * 64 + e] = (__bf16)v;
        }
      }
    }
  } else {
    #pragma unroll
    for (int mt = 0; mt < 4; mt++) {
      #pragma unroll
      for (int r = 0; r < 4; r++) {
        long m = m0 + wm + mt * 16 + quad * 4 + r;
        #pragma unroll
        for (int nt = 0; nt < 4; nt++) {
          long n = n0 + wn + nt * 16 + l15;
          out[m * N + n] = acc[mt][nt][r] + bo[n];
        }
      }
    }
  }
}

// ---------------------------------------------------------------------------
// NAIVE attention (correctness anchor): no MFMA, no cross-lane ops.
// grid (S/256, H, B), block 256. One thread = one query row; serial online
// softmax over 2048 keys, K/V staged per-128-key tile in fp32 LDS.
// Q pre-scaled by 0.125. Reads q/k/v [B,H,S,64] bf16; writes vout [B,S,H,64].
// ---------------------------------------------------------------------------
__global__ __launch_bounds__(256, 2) void naive_attn_kernel(
    const __bf16* __restrict__ Q, const __bf16* __restrict__ K,
    const __bf16* __restrict__ V, __bf16* __restrict__ vout) {

  __shared__ float Ks[128 * 64];
  __shared__ float Vs[128 * 64];

  int tid = threadIdx.x;
  int b = blockIdx.z, h = blockIdx.y;
  int s = blockIdx.x * 256 + tid;

  const __bf16* Qr  = Q + ((long)(b * 16 + h) * 2048 + s) * 64;
  const __bf16* Kbh = K + (long)(b * 16 + h) * 2048 * 64;
  const __bf16* Vbh = V + (long)(b * 16 + h) * 2048 * 64;

  float4 q4[16], o4[16];
  #pragma unroll
  for (int t = 0; t < 8; t++) {
    bf16x8 qv = *(const bf16x8*)(Qr + t * 8);
    q4[2 * t]     = make_float4((float)qv[0], (float)qv[1], (float)qv[2], (float)qv[3]);
    q4[2 * t + 1] = make_float4((float)qv[4], (float)qv[5], (float)qv[6], (float)qv[7]);
    o4[2 * t]     = make_float4(0.f, 0.f, 0.f, 0.f);
    o4[2 * t + 1] = make_float4(0.f, 0.f, 0.f, 0.f);
  }
  float m = -1e30f, l = 0.f;
  const float L2E = 1.44269504088896340f;

  for (int kb = 0; kb < 2048; kb += 128) {
    __syncthreads();   // WAR: previous tile's reads complete
    for (int c = tid; c < 1024; c += 256) {
      int row = c >> 3, off = (c & 7) * 8;
      bf16x8 kv = *(const bf16x8*)(Kbh + (long)(kb + row) * 64 + off);
      bf16x8 vv = *(const bf16x8*)(Vbh + (long)(kb + row) * 64 + off);
      #pragma unroll
      for (int j = 0; j < 8; j++) {
        Ks[row * 64 + off + j] = (float)kv[j];
        Vs[row * 64 + off + j] = (float)vv[j];
      }
    }
    __syncthreads();
    for (int key = 0; key < 128; key++) {
      const float4* K4 = (const float4*)&Ks[key * 64];
      float sv = 0.f;
      #pragma unroll
      for (int e = 0; e < 16; e++) {
        float4 kx = K4[e];
        sv += q4[e].x * kx.x + q4[e].y * kx.y + q4[e].z * kx.z + q4[e].w * kx.w;
      }
      float mn = fmaxf(m, sv);
      float alpha = exp2f((m - mn) * L2E);
      float p = exp2f((sv - mn) * L2E);
      l = l * alpha + p;
      const float4* V4 = (const float4*)&Vs[key * 64];
      #pragma unroll
      for (int e = 0; e < 16; e++) {
        float4 vx = V4[e];
        o4[e].x = o4[e].x * alpha + p * vx.x;
        o4[e].y = o4[e].y * alpha + p * vx.y;
        o4[e].z = o4[e].z * alpha + p * vx.z;
        o4[e].w = o4[e].w * alpha + p * vx.w;
      }
      m = mn;
    }
  }

  float rl = 1.f / l;
  __bf16* outr = vout + ((long)(b * 2048 + s) * 16 + h) * 64;
  #pragma unroll
  for (int t = 0; t < 8; t++) {
    float4 a = o4[2 * t], c = o4[2 * t + 1];
    bf16x8 w;
    w[0] = (__bf16)(a.x * rl); w[1] = (__bf16)(a.y * rl);
    w[2] = (__bf16)(a.z * rl); w[3] = (__bf16)(a.w * rl);
    w[4] = (__bf16)(c.x * rl); w[5] = (__bf16)(c.y * rl);
    w[6] = (__bf16)(c.z * rl); w[7] = (__bf16)(c.w * rl);
    *(bf16x8*)(outr + t * 8) = w;
  }
}

// ---------------------------------------------------------------------------
extern "C" void kernel_launch(void* const* d_in, const int* in_sizes, int n_in,
                              void* d_out, int out_size, void* d_ws, size_t ws_size,
                              hipStream_t stream) {
  const float* x  = (const float*)d_in[0];
  const float* WQ = (const float*)d_in[1];
  const float* WK = (const float*)d_in[2];
  const float* WV = (const float*)d_in[3];
  const float* WO = (const float*)d_in[4];
  const float* bq = (const float*)d_in[5];
  const float* bk = (const float*)d_in[6];
  const float* bv = (const float*)d_in[7];
  const float* bo = (const float*)d_in[8];
  float* out = (float*)d_out;

  // Workspace: exactly 64 MiB via lifetime overlap (all bf16 internals).
  //   [0,16M)   q_ws  (dead after attn)
  //   [16,32M)  k_ws
  //   [32,48M)  v_ws
  //   [48,54M)  Wt    (dead after gemm<0>)
  //   [48,64M)  vout  (written by attn, after Wt dies)
  //   [0,2M)    WOt   (transposed after attn, into dead q_ws)
  uint8_t* ws = (uint8_t*)d_ws;
  const long MB16 = 16777216;
  __bf16* q_ws = (__bf16*)(ws);
  __bf16* k_ws = (__bf16*)(ws + 1 * MB16);
  __bf16* v_ws = (__bf16*)(ws + 2 * MB16);
  __bf16* Wt   = (__bf16*)(ws + 3 * MB16);   // [3072][1024], 6 MiB
  __bf16* vout = (__bf16*)(ws + 3 * MB16);   // [B,S,H,64], 16 MiB
  __bf16* WOt  = (__bf16*)(ws);              // [1024][1024], 2 MiB

  dim3 tb(32, 8);
  // W_Q/K/V: per-head fp32 [1024 d][64 e] -> bf16 [64 e][1024 d], heads concat
  transpose_kernel<<<dim3(2, 32, 16), tb, 0, stream>>>(WQ, Wt,               1024, 64, 65536, 65536);
  transpose_kernel<<<dim3(2, 32, 16), tb, 0, stream>>>(WK, Wt + 1024 * 1024, 1024, 64, 65536, 65536);
  transpose_kernel<<<dim3(2, 32, 16), tb, 0, stream>>>(WV, Wt + 2048 * 1024, 1024, 64, 65536, 65536);

  // fused QKV projection: fp32 x [8192 x 1024] * bf16 Wt -> bf16 Q/K/V
  gemm_kernel<0><<<dim3(3072 / BN, 8192 / BM), 256, 0, stream>>>(
      x, Wt, BS_, 3072, DM_, bq, bk, bv, nullptr, q_ws, k_ws, v_ws, nullptr);

  // naive attention (correctness anchor)
  naive_attn_kernel<<<dim3(S_ / 256, H_, B_), 256, 0, stream>>>(q_ws, k_ws, v_ws, vout);

  // W_O: fp32 [1024 he][1024 d] -> bf16 [1024 d][1024 he] (into dead q_ws)
  transpose_kernel<<<dim3(32, 32, 1), tb, 0, stream>>>(WO, WOt, 1024, 1024, 0, 0);

  // output projection: bf16 vout [8192 x 1024] * bf16 WOt -> fp32 out + b_O
  gemm_kernel<1><<<dim3(1024 / BN, 8192 / BM), 256, 0, stream>>>(
      vout, WOt, BS_, DM_, DM_, nullptr, nullptr, nullptr, bo, nullptr, nullptr, nullptr, out);
}

// Round 5
// 732.596 us; speedup vs baseline: 3.2873x; 3.2873x over previous
//
#include <hip/hip_runtime.h>
#include <hip/hip_bf16.h>
#include <cmath>

// Problem constants. I/O is FP32 (per reference); internals bf16.
#define B_ 4
#define S_ 2048
#define DM_ 1024
#define H_ 16
#define DH_ 64
#define BS_ (B_*S_)   // 8192 rows

typedef __bf16 bf16x8 __attribute__((ext_vector_type(8)));
typedef float  floatx4 __attribute__((ext_vector_type(4)));

// ---------------------------------------------------------------------------
// Batched 32x32 transpose: fp32 src[R][C] -> bf16 dst[C][R] (per batch)
// ---------------------------------------------------------------------------
__global__ void transpose_kernel(const float* __restrict__ src, __bf16* __restrict__ dst,
                                 int R, int C, long srcBatch, long dstBatch) {
  __shared__ __bf16 tile[32][33];
  int b = blockIdx.z;
  long sb = (long)b * srcBatch;
  dst += (long)b * dstBatch;
  int c0 = blockIdx.x * 32, r0 = blockIdx.y * 32;
  int tx = threadIdx.x, ty = threadIdx.y;      // block (32, 8)
  #pragma unroll
  for (int i = 0; i < 32; i += 8)
    tile[ty + i][tx] = (__bf16)src[sb + (long)(r0 + ty + i) * C + (c0 + tx)];
  __syncthreads();
  #pragma unroll
  for (int i = 0; i < 32; i += 8)
    dst[(long)(c0 + ty + i) * R + (r0 + tx)] = tile[tx][ty + i];
}

// ---------------------------------------------------------------------------
// Tiled MFMA GEMM: C[M][N] = A[M][K] * B[K][N], B supplied TRANSPOSED
// (bf16 Bt[N][K]). BM=BN=128, BK=64. 256 threads = 4 waves, wave = 64x64.
// EPI==0: A is FP32 (x), epilogue -> Q(*0.125)/K bf16 [B,H,S,64],
//         V bf16 TRANSPOSED [B,H,64,S]; fp32 biases
// EPI==1: A is bf16 (vout), epilogue -> fp32 out[M][N] + fp32 bias
// ---------------------------------------------------------------------------
#define BM 128
#define BN 128
#define BK 64
#define LDK 72   // padded LDS row stride (elements)

template<int EPI>
__global__ __launch_bounds__(256, 2) void gemm_kernel(
    const void* __restrict__ Avoid, const __bf16* __restrict__ Bt,
    int M, int N, int K,
    const float* __restrict__ bq, const float* __restrict__ bk,
    const float* __restrict__ bv, const float* __restrict__ bo,
    __bf16* __restrict__ q_ws, __bf16* __restrict__ k_ws,
    __bf16* __restrict__ vT_ws, float* __restrict__ out) {

  __shared__ __align__(16) __bf16 As[BM * LDK];
  __shared__ __align__(16) __bf16 Bs[BN * LDK];

  int tid  = threadIdx.x;
  int wave = tid >> 6, lane = tid & 63;
  int quad = lane >> 4, l15 = lane & 15;
  int wm = (wave >> 1) * 64, wn = (wave & 1) * 64;
  long m0 = (long)blockIdx.y * BM;
  long n0 = (long)blockIdx.x * BN;

  floatx4 acc[4][4] = {};   // [mt][nt]

  int arow  = tid >> 1;              // 0..127
  int ahalf = (tid & 1) * 32;        // element offset 0 or 32
  const float*  Af = (const float*) Avoid;   // EPI==0
  const __bf16* Ab = (const __bf16*)Avoid;   // EPI==1
  const __bf16* Bptr = Bt + (n0 + arow) * (long)K + ahalf;

  for (int k0 = 0; k0 < K; k0 += BK) {
    bf16x8 avb[4], bvv[4];
    if (EPI == 0) {
      const float* Ap = Af + (m0 + arow) * (long)K + ahalf + k0;
      #pragma unroll
      for (int c = 0; c < 4; c++) {
        float4 lo = *(const float4*)(Ap + c * 8);
        float4 hi = *(const float4*)(Ap + c * 8 + 4);
        bf16x8 t;
        t[0] = (__bf16)lo.x; t[1] = (__bf16)lo.y; t[2] = (__bf16)lo.z; t[3] = (__bf16)lo.w;
        t[4] = (__bf16)hi.x; t[5] = (__bf16)hi.y; t[6] = (__bf16)hi.z; t[7] = (__bf16)hi.w;
        avb[c] = t;
      }
    } else {
      const __bf16* Ap = Ab + (m0 + arow) * (long)K + ahalf + k0;
      #pragma unroll
      for (int c = 0; c < 4; c++) avb[c] = *(const bf16x8*)(Ap + c * 8);
    }
    #pragma unroll
    for (int c = 0; c < 4; c++) bvv[c] = *(const bf16x8*)(Bptr + k0 + c * 8);

    __syncthreads();   // WAR: previous iter's fragment reads done before overwrite
    #pragma unroll
    for (int c = 0; c < 4; c++) *(bf16x8*)(&As[arow * LDK + ahalf + c * 8]) = avb[c];
    #pragma unroll
    for (int c = 0; c < 4; c++) *(bf16x8*)(&Bs[arow * LDK + ahalf + c * 8]) = bvv[c];
    __syncthreads();

    #pragma unroll
    for (int kk = 0; kk < 2; kk++) {
      bf16x8 af[4], bff[4];
      #pragma unroll
      for (int mt = 0; mt < 4; mt++)
        af[mt] = *(const bf16x8*)(&As[(wm + mt * 16 + l15) * LDK + kk * 32 + quad * 8]);
      #pragma unroll
      for (int nt = 0; nt < 4; nt++)
        bff[nt] = *(const bf16x8*)(&Bs[(wn + nt * 16 + l15) * LDK + kk * 32 + quad * 8]);
      #pragma unroll
      for (int mt = 0; mt < 4; mt++)
        #pragma unroll
        for (int nt = 0; nt < 4; nt++)
          acc[mt][nt] = __builtin_amdgcn_mfma_f32_16x16x32_bf16(af[mt], bff[nt], acc[mt][nt], 0, 0, 0);
    }
  }

  if (EPI == 0) {
    // n in [0,3072): seg 0=Q,1=K,2=V ; h=(n&1023)>>6 ; e=n&63
    #pragma unroll
    for (int nt = 0; nt < 4; nt++) {
      long n = n0 + wn + nt * 16 + l15;
      int seg = (int)(n >> 10);
      int he  = (int)(n & 1023);
      int h = he >> 6, e = he & 63;
      const float* bias = (seg == 0 ? bq : (seg == 1 ? bk : bv));
      float bval = bias[he];
      float scale = (seg == 0 ? 0.125f : 1.0f);   // fold 1/sqrt(64) into Q
      #pragma unroll
      for (int mt = 0; mt < 4; mt++) {
        #pragma unroll
        for (int r = 0; r < 4; r++) {
          long m = m0 + wm + mt * 16 + quad * 4 + r;
          int b = (int)(m >> 11), s = (int)(m & 2047);
          float v = (acc[mt][nt][r] + bval) * scale;
          if (seg == 0)
            q_ws[((long)(b * 16 + h) * 2048 + s) * 64 + e] = (__bf16)v;
          else if (seg == 1)
            k_ws[((long)(b * 16 + h) * 2048 + s) * 64 + e] = (__bf16)v;
          else   // V transposed: [B,H,64,S]
            vT_ws[((long)(b * 16 + h) * 64 + e) * 2048 + s] = (__bf16)v;
        }
      }
    }
  } else {
    #pragma unroll
    for (int mt = 0; mt < 4; mt++) {
      #pragma unroll
      for (int r = 0; r < 4; r++) {
        long m = m0 + wm + mt * 16 + quad * 4 + r;
        #pragma unroll
        for (int nt = 0; nt < 4; nt++) {
          long n = n0 + wn + nt * 16 + l15;
          out[m * N + n] = acc[mt][nt][r] + bo[n];
        }
      }
    }
  }
}

// ---------------------------------------------------------------------------
// Flash attention (MFMA): grid (S/64, H, B); block 256 = 4 waves, wave = 16
// q-rows. Q,K: [B,H,S,64] bf16 (Q pre-scaled by 0.125); Vt: [B,H,64,S] bf16.
// Online softmax in fp32 (finite -1e30 init); P: C-layout -> LDS -> A-layout.
// Writes vout [B,S,H,64] bf16.
// ---------------------------------------------------------------------------
__global__ __launch_bounds__(256, 2) void attn_kernel(
    const __bf16* __restrict__ Q, const __bf16* __restrict__ Kk,
    const __bf16* __restrict__ Vt, __bf16* __restrict__ vout) {

  __shared__ __align__(16) __bf16 Plds[4][16 * LDK];

  int tid = threadIdx.x, wave = tid >> 6, lane = tid & 63;
  int quad = lane >> 4, l15 = lane & 15;
  int b = blockIdx.z, h = blockIdx.y;
  int q0 = blockIdx.x * 64 + wave * 16;

  const __bf16* Qbh = Q  + (long)(b * 16 + h) * 2048 * 64;
  const __bf16* Kbh = Kk + (long)(b * 16 + h) * 2048 * 64;
  const __bf16* Vbh = Vt + (long)(b * 16 + h) * 64 * 2048;

  bf16x8 qf[2];
  #pragma unroll
  for (int t = 0; t < 2; t++)
    qf[t] = *(const bf16x8*)(Qbh + (long)(q0 + l15) * 64 + t * 32 + quad * 8);

  floatx4 o[4] = {};             // 16 q-rows x 64 d, C-layout frags per dn
  float mrow[4], lrow[4];
  #pragma unroll
  for (int r = 0; r < 4; r++) { mrow[r] = -1e30f; lrow[r] = 0.f; }
  __bf16* P = Plds[wave];
  const float L2E = 1.44269504088896340f;

  for (int kb = 0; kb < 2048; kb += 64) {
    // scores: 16 x 64 (already scaled via Q)
    floatx4 sc[4] = {};
    #pragma unroll
    for (int nt = 0; nt < 4; nt++) {
      #pragma unroll
      for (int t = 0; t < 2; t++) {
        bf16x8 kf = *(const bf16x8*)(Kbh + (long)(kb + nt * 16 + l15) * 64 + t * 32 + quad * 8);
        sc[nt] = __builtin_amdgcn_mfma_f32_16x16x32_bf16(qf[t], kf, sc[nt], 0, 0, 0);
      }
    }
    // per-row tile max (reduce across the 16 lanes sharing this quad-row)
    float alpha[4];
    #pragma unroll
    for (int r = 0; r < 4; r++) {
      float tm = fmaxf(fmaxf(sc[0][r], sc[1][r]), fmaxf(sc[2][r], sc[3][r]));
      #pragma unroll
      for (int off = 1; off < 16; off <<= 1) tm = fmaxf(tm, __shfl_xor(tm, off, 64));
      float mnew = fmaxf(mrow[r], tm);
      alpha[r] = exp2f((mrow[r] - mnew) * L2E);
      mrow[r] = mnew;
    }
    __syncthreads();   // WAR on P from previous iteration's reads
    float rsum[4] = {0.f, 0.f, 0.f, 0.f};
    #pragma unroll
    for (int nt = 0; nt < 4; nt++) {
      #pragma unroll
      for (int r = 0; r < 4; r++) {
        float p = exp2f((sc[nt][r] - mrow[r]) * L2E);
        rsum[r] += p;
        P[(quad * 4 + r) * LDK + nt * 16 + l15] = (__bf16)p;
      }
    }
    #pragma unroll
    for (int r = 0; r < 4; r++) {
      float s = rsum[r];
      #pragma unroll
      for (int off = 1; off < 16; off <<= 1) s += __shfl_xor(s, off, 64);
      lrow[r] = alpha[r] * lrow[r] + s;
    }
    #pragma unroll
    for (int dn = 0; dn < 4; dn++)
      #pragma unroll
      for (int r = 0; r < 4; r++) o[dn][r] *= alpha[r];
    __syncthreads();   // P writes visible for A-layout reads
    #pragma unroll
    for (int t = 0; t < 2; t++) {
      bf16x8 pf = *(const bf16x8*)(&P[l15 * LDK + t * 32 + quad * 8]);
      #pragma unroll
      for (int dn = 0; dn < 4; dn++) {
        bf16x8 vf = *(const bf16x8*)(Vbh + (long)(dn * 16 + l15) * 2048 + kb + t * 32 + quad * 8);
        o[dn] = __builtin_amdgcn_mfma_f32_16x16x32_bf16(pf, vf, o[dn], 0, 0, 0);
      }
    }
  }

  // write v_out as [B, S, H, 64] (he contiguous for O-projection A-operand)
  #pragma unroll
  for (int dn = 0; dn < 4; dn++) {
    #pragma unroll
    for (int r = 0; r < 4; r++) {
      int s = q0 + quad * 4 + r;
      int e = dn * 16 + l15;
      vout[((long)(b * 2048 + s) * 16 + h) * 64 + e] = (__bf16)(o[dn][r] / lrow[r]);
    }
  }
}

// ---------------------------------------------------------------------------
extern "C" void kernel_launch(void* const* d_in, const int* in_sizes, int n_in,
                              void* d_out, int out_size, void* d_ws, size_t ws_size,
                              hipStream_t stream) {
  const float* x  = (const float*)d_in[0];
  const float* WQ = (const float*)d_in[1];
  const float* WK = (const float*)d_in[2];
  const float* WV = (const float*)d_in[3];
  const float* WO = (const float*)d_in[4];
  const float* bq = (const float*)d_in[5];
  const float* bk = (const float*)d_in[6];
  const float* bv = (const float*)d_in[7];
  const float* bo = (const float*)d_in[8];
  float* out = (float*)d_out;

  // Workspace: exactly 64 MiB via lifetime overlap (all bf16 internals).
  //   [0,16M)   q_ws  (dead after attn)
  //   [16,32M)  k_ws
  //   [32,48M)  vT_ws
  //   [48,54M)  Wt    (dead after gemm<0>)
  //   [48,64M)  vout  (written by attn, after Wt dies)
  //   [0,2M)    WOt   (transposed after attn, into dead q_ws)
  uint8_t* ws = (uint8_t*)d_ws;
  const long MB16 = 16777216;
  __bf16* q_ws  = (__bf16*)(ws);
  __bf16* k_ws  = (__bf16*)(ws + 1 * MB16);
  __bf16* vT_ws = (__bf16*)(ws + 2 * MB16);
  __bf16* Wt    = (__bf16*)(ws + 3 * MB16);   // [3072][1024], 6 MiB
  __bf16* vout  = (__bf16*)(ws + 3 * MB16);   // [B,S,H,64], 16 MiB
  __bf16* WOt   = (__bf16*)(ws);              // [1024][1024], 2 MiB

  dim3 tb(32, 8);
  // W_Q/K/V: per-head fp32 [1024 d][64 e] -> bf16 [64 e][1024 d], heads concat
  transpose_kernel<<<dim3(2, 32, 16), tb, 0, stream>>>(WQ, Wt,               1024, 64, 65536, 65536);
  transpose_kernel<<<dim3(2, 32, 16), tb, 0, stream>>>(WK, Wt + 1024 * 1024, 1024, 64, 65536, 65536);
  transpose_kernel<<<dim3(2, 32, 16), tb, 0, stream>>>(WV, Wt + 2048 * 1024, 1024, 64, 65536, 65536);

  // fused QKV projection: fp32 x [8192 x 1024] * bf16 Wt -> bf16 Q/K/V^T
  gemm_kernel<0><<<dim3(3072 / BN, 8192 / BM), 256, 0, stream>>>(
      x, Wt, BS_, 3072, DM_, bq, bk, bv, nullptr, q_ws, k_ws, vT_ws, nullptr);

  // flash attention (MFMA)
  attn_kernel<<<dim3(S_ / 64, H_, B_), 256, 0, stream>>>(q_ws, k_ws, vT_ws, vout);

  // W_O: fp32 [1024 he][1024 d] -> bf16 [1024 d][1024 he] (into dead q_ws)
  transpose_kernel<<<dim3(32, 32, 1), tb, 0, stream>>>(WO, WOt, 1024, 1024, 0, 0);

  // output projection: bf16 vout [8192 x 1024] * bf16 WOt -> fp32 out + b_O
  gemm_kernel<1><<<dim3(1024 / BN, 8192 / BM), 256, 0, stream>>>(
      vout, WOt, BS_, DM_, DM_, nullptr, nullptr, nullptr, bo, nullptr, nullptr, nullptr, out);
}

// Round 6
// 505.569 us; speedup vs baseline: 4.7635x; 1.4491x over previous
//
#include <hip/hip_runtime.h>
#include <hip/hip_bf16.h>
#include <cmath>

// Problem constants. I/O is FP32 (per reference); internals bf16.
#define B_ 4
#define S_ 2048
#define DM_ 1024
#define H_ 16
#define DH_ 64
#define BS_ (B_*S_)   // 8192 rows

typedef __bf16 bf16x8 __attribute__((ext_vector_type(8)));
typedef __bf16 bf16x4 __attribute__((ext_vector_type(4)));
typedef float  floatx4 __attribute__((ext_vector_type(4)));

// ---------------------------------------------------------------------------
// Batched 32x32 transpose: fp32 src[R][C] -> bf16 dst[C][R] (per batch)
// ---------------------------------------------------------------------------
__global__ void transpose_kernel(const float* __restrict__ src, __bf16* __restrict__ dst,
                                 int R, int C, long srcBatch, long dstBatch) {
  __shared__ __bf16 tile[32][33];
  int b = blockIdx.z;
  long sb = (long)b * srcBatch;
  dst += (long)b * dstBatch;
  int c0 = blockIdx.x * 32, r0 = blockIdx.y * 32;
  int tx = threadIdx.x, ty = threadIdx.y;      // block (32, 8)
  #pragma unroll
  for (int i = 0; i < 32; i += 8)
    tile[ty + i][tx] = (__bf16)src[sb + (long)(r0 + ty + i) * C + (c0 + tx)];
  __syncthreads();
  #pragma unroll
  for (int i = 0; i < 32; i += 8)
    dst[(long)(c0 + ty + i) * R + (r0 + tx)] = tile[tx][ty + i];
}

// ---------------------------------------------------------------------------
// Tiled MFMA GEMM: C[M][N] = A[M][K] * B[K][N], B supplied TRANSPOSED
// (bf16 Bt[N][K]). BM=BN=128, BK=64. 256 threads = 4 waves, wave = 64x64.
// EPI==0: A is FP32 (x), epilogue -> Q(*0.125)/K bf16 [B,H,S,64],
//         V bf16 TRANSPOSED [B,H,64,S]; fp32 biases
// EPI==1: A is bf16 (vout), epilogue -> fp32 out[M][N] + fp32 bias
// ---------------------------------------------------------------------------
#define BM 128
#define BN 128
#define BK 64
#define LDK 72   // padded LDS row stride (elements)

template<int EPI>
__global__ __launch_bounds__(256, 2) void gemm_kernel(
    const void* __restrict__ Avoid, const __bf16* __restrict__ Bt,
    int M, int N, int K,
    const float* __restrict__ bq, const float* __restrict__ bk,
    const float* __restrict__ bv, const float* __restrict__ bo,
    __bf16* __restrict__ q_ws, __bf16* __restrict__ k_ws,
    __bf16* __restrict__ vT_ws, float* __restrict__ out) {

  __shared__ __align__(16) __bf16 As[BM * LDK];
  __shared__ __align__(16) __bf16 Bs[BN * LDK];

  int tid  = threadIdx.x;
  int wave = tid >> 6, lane = tid & 63;
  int quad = lane >> 4, l15 = lane & 15;
  int wm = (wave >> 1) * 64, wn = (wave & 1) * 64;
  long m0 = (long)blockIdx.y * BM;
  long n0 = (long)blockIdx.x * BN;

  floatx4 acc[4][4] = {};   // [mt][nt]

  int arow  = tid >> 1;              // 0..127
  int ahalf = (tid & 1) * 32;        // element offset 0 or 32
  const float*  Af = (const float*) Avoid;   // EPI==0
  const __bf16* Ab = (const __bf16*)Avoid;   // EPI==1
  const __bf16* Bptr = Bt + (n0 + arow) * (long)K + ahalf;

  for (int k0 = 0; k0 < K; k0 += BK) {
    bf16x8 avb[4], bvv[4];
    if (EPI == 0) {
      const float* Ap = Af + (m0 + arow) * (long)K + ahalf + k0;
      #pragma unroll
      for (int c = 0; c < 4; c++) {
        float4 lo = *(const float4*)(Ap + c * 8);
        float4 hi = *(const float4*)(Ap + c * 8 + 4);
        bf16x8 t;
        t[0] = (__bf16)lo.x; t[1] = (__bf16)lo.y; t[2] = (__bf16)lo.z; t[3] = (__bf16)lo.w;
        t[4] = (__bf16)hi.x; t[5] = (__bf16)hi.y; t[6] = (__bf16)hi.z; t[7] = (__bf16)hi.w;
        avb[c] = t;
      }
    } else {
      const __bf16* Ap = Ab + (m0 + arow) * (long)K + ahalf + k0;
      #pragma unroll
      for (int c = 0; c < 4; c++) avb[c] = *(const bf16x8*)(Ap + c * 8);
    }
    #pragma unroll
    for (int c = 0; c < 4; c++) bvv[c] = *(const bf16x8*)(Bptr + k0 + c * 8);

    __syncthreads();   // WAR: previous iter's fragment reads done before overwrite
    #pragma unroll
    for (int c = 0; c < 4; c++) *(bf16x8*)(&As[arow * LDK + ahalf + c * 8]) = avb[c];
    #pragma unroll
    for (int c = 0; c < 4; c++) *(bf16x8*)(&Bs[arow * LDK + ahalf + c * 8]) = bvv[c];
    __syncthreads();

    #pragma unroll
    for (int kk = 0; kk < 2; kk++) {
      bf16x8 af[4], bff[4];
      #pragma unroll
      for (int mt = 0; mt < 4; mt++)
        af[mt] = *(const bf16x8*)(&As[(wm + mt * 16 + l15) * LDK + kk * 32 + quad * 8]);
      #pragma unroll
      for (int nt = 0; nt < 4; nt++)
        bff[nt] = *(const bf16x8*)(&Bs[(wn + nt * 16 + l15) * LDK + kk * 32 + quad * 8]);
      #pragma unroll
      for (int mt = 0; mt < 4; mt++)
        #pragma unroll
        for (int nt = 0; nt < 4; nt++)
          acc[mt][nt] = __builtin_amdgcn_mfma_f32_16x16x32_bf16(af[mt], bff[nt], acc[mt][nt], 0, 0, 0);
    }
  }

  if (EPI == 0) {
    // n in [0,3072): seg 0=Q,1=K,2=V ; h=(n&1023)>>6 ; e=n&63
    #pragma unroll
    for (int nt = 0; nt < 4; nt++) {
      long n = n0 + wn + nt * 16 + l15;
      int seg = (int)(n >> 10);
      int he  = (int)(n & 1023);
      int h = he >> 6, e = he & 63;
      const float* bias = (seg == 0 ? bq : (seg == 1 ? bk : bv));
      float bval = bias[he];
      float scale = (seg == 0 ? 0.125f : 1.0f);   // fold 1/sqrt(64) into Q
      #pragma unroll
      for (int mt = 0; mt < 4; mt++) {
        #pragma unroll
        for (int r = 0; r < 4; r++) {
          long m = m0 + wm + mt * 16 + quad * 4 + r;
          int b = (int)(m >> 11), s = (int)(m & 2047);
          float v = (acc[mt][nt][r] + bval) * scale;
          if (seg == 0)
            q_ws[((long)(b * 16 + h) * 2048 + s) * 64 + e] = (__bf16)v;
          else if (seg == 1)
            k_ws[((long)(b * 16 + h) * 2048 + s) * 64 + e] = (__bf16)v;
          else   // V transposed: [B,H,64,S]
            vT_ws[((long)(b * 16 + h) * 64 + e) * 2048 + s] = (__bf16)v;
        }
      }
    }
  } else {
    #pragma unroll
    for (int mt = 0; mt < 4; mt++) {
      #pragma unroll
      for (int r = 0; r < 4; r++) {
        long m = m0 + wm + mt * 16 + quad * 4 + r;
        #pragma unroll
        for (int nt = 0; nt < 4; nt++) {
          long n = n0 + wn + nt * 16 + l15;
          out[m * N + n] = acc[mt][nt][r] + bo[n];
        }
      }
    }
  }
}

// ---------------------------------------------------------------------------
// Flash attention, operand-swapped (S^T / O^T): grid (S/128, H, B); block 256
// = 4 waves; each wave owns 32 q-rows (2 q-frags). No __syncthreads: P is
// wave-private, DS ops are in-order per wave.
//   QK^T: mfma(kf, qf) -> Sc^T[key][q], col=q=lane&15 -> per-lane softmax
//         state (in-lane max/sum over 16 regs + 2 shuffles across quads).
//   PV:   mfma(vf, pf) -> O^T[d][q], alpha rescale lane-uniform.
// Q,K: [B,H,S,64] bf16 (Q pre-scaled by 0.125); Vt: [B,H,64,S] bf16.
// Writes vout [B,S,H,64] bf16.
// ---------------------------------------------------------------------------
#define LDP 72   // P row stride (elems): 144 B, 16B-aligned

__global__ __launch_bounds__(256, 2) void attn_kernel(
    const __bf16* __restrict__ Q, const __bf16* __restrict__ Kk,
    const __bf16* __restrict__ Vt, __bf16* __restrict__ vout) {

  __shared__ __align__(16) __bf16 Plds[4][2][16 * LDP];

  int tid = threadIdx.x, wave = tid >> 6, lane = tid & 63;
  int quad = lane >> 4, l15 = lane & 15;
  int b = blockIdx.z, h = blockIdx.y;
  int q0 = blockIdx.x * 128 + wave * 32;

  const __bf16* Qbh = Q  + (long)(b * 16 + h) * 2048 * 64;
  const __bf16* Kbh = Kk + (long)(b * 16 + h) * 2048 * 64;
  const __bf16* Vbh = Vt + (long)(b * 16 + h) * 64 * 2048;

  // Q fragments (B-operand): lane holds Q[q0+qh*16+l15][quad*8+j (+32)]
  bf16x8 qf[2][2];
  #pragma unroll
  for (int qh = 0; qh < 2; qh++)
    #pragma unroll
    for (int t = 0; t < 2; t++)
      qf[qh][t] = *(const bf16x8*)(Qbh + (long)(q0 + qh * 16 + l15) * 64 + t * 32 + quad * 8);

  floatx4 o[2][4] = {};           // O^T frags: [qh][dn]; row=d, col=q=l15
  float mrow[2] = { -1e30f, -1e30f };
  float lrow[2] = { 0.f, 0.f };
  const float L2E = 1.44269504088896340f;

  for (int kb = 0; kb < 2048; kb += 64) {
    // Sc^T[key][q]: 2 qh x 4 nt frags
    floatx4 sc[2][4];
    #pragma unroll
    for (int nt = 0; nt < 4; nt++) {
      const __bf16* kp = Kbh + (long)(kb + nt * 16 + l15) * 64 + quad * 8;
      bf16x8 kf0 = *(const bf16x8*)kp;
      bf16x8 kf1 = *(const bf16x8*)(kp + 32);
      #pragma unroll
      for (int qh = 0; qh < 2; qh++) {
        floatx4 z = { 0.f, 0.f, 0.f, 0.f };
        z = __builtin_amdgcn_mfma_f32_16x16x32_bf16(kf0, qf[qh][0], z, 0, 0, 0);
        sc[qh][nt] = __builtin_amdgcn_mfma_f32_16x16x32_bf16(kf1, qf[qh][1], z, 0, 0, 0);
      }
    }
    // per-q-row online softmax (lane owns q=l15; reduce over 16 regs + quads)
    #pragma unroll
    for (int qh = 0; qh < 2; qh++) {
      float tm = sc[qh][0][0];
      #pragma unroll
      for (int nt = 0; nt < 4; nt++)
        #pragma unroll
        for (int r = 0; r < 4; r++) tm = fmaxf(tm, sc[qh][nt][r]);
      tm = fmaxf(tm, __shfl_xor(tm, 16, 64));
      tm = fmaxf(tm, __shfl_xor(tm, 32, 64));
      float mnew = fmaxf(mrow[qh], tm);
      float alpha = __builtin_exp2f((mrow[qh] - mnew) * L2E);
      mrow[qh] = mnew;

      __bf16* Pq = &Plds[wave][qh][0];
      float rs = 0.f;
      #pragma unroll
      for (int nt = 0; nt < 4; nt++) {
        bf16x4 pw;
        #pragma unroll
        for (int r = 0; r < 4; r++) {
          float p = __builtin_exp2f((sc[qh][nt][r] - mnew) * L2E);
          rs += p;
          pw[r] = (__bf16)p;
        }
        *(bf16x4*)(&Pq[l15 * LDP + nt * 16 + quad * 4]) = pw;   // P[q][key], 4 keys
      }
      rs += __shfl_xor(rs, 16, 64);
      rs += __shfl_xor(rs, 32, 64);
      lrow[qh] = alpha * lrow[qh] + rs;
      #pragma unroll
      for (int dn = 0; dn < 4; dn++) o[qh][dn] *= alpha;   // lane-uniform alpha
    }
    // O^T += V^T x P^T  (vf shared across both q-halves)
    #pragma unroll
    for (int t = 0; t < 2; t++) {
      bf16x8 pf0 = *(const bf16x8*)(&Plds[wave][0][l15 * LDP + t * 32 + quad * 8]);
      bf16x8 pf1 = *(const bf16x8*)(&Plds[wave][1][l15 * LDP + t * 32 + quad * 8]);
      #pragma unroll
      for (int dn = 0; dn < 4; dn++) {
        bf16x8 vf = *(const bf16x8*)(Vbh + (long)(dn * 16 + l15) * 2048 + kb + t * 32 + quad * 8);
        o[0][dn] = __builtin_amdgcn_mfma_f32_16x16x32_bf16(vf, pf0, o[0][dn], 0, 0, 0);
        o[1][dn] = __builtin_amdgcn_mfma_f32_16x16x32_bf16(vf, pf1, o[1][dn], 0, 0, 0);
      }
    }
  }

  // write O^T -> vout [B,S,H,64]: lane q=l15, e=dn*16+quad*4+r (b64 stores)
  #pragma unroll
  for (int qh = 0; qh < 2; qh++) {
    float rl = 1.f / lrow[qh];
    int s = q0 + qh * 16 + l15;
    __bf16* outr = vout + ((long)(b * 2048 + s) * 16 + h) * 64;
    #pragma unroll
    for (int dn = 0; dn < 4; dn++) {
      bf16x4 w;
      #pragma unroll
      for (int r = 0; r < 4; r++) w[r] = (__bf16)(o[qh][dn][r] * rl);
      *(bf16x4*)(outr + dn * 16 + quad * 4) = w;
    }
  }
}

// ---------------------------------------------------------------------------
extern "C" void kernel_launch(void* const* d_in, const int* in_sizes, int n_in,
                              void* d_out, int out_size, void* d_ws, size_t ws_size,
                              hipStream_t stream) {
  const float* x  = (const float*)d_in[0];
  const float* WQ = (const float*)d_in[1];
  const float* WK = (const float*)d_in[2];
  const float* WV = (const float*)d_in[3];
  const float* WO = (const float*)d_in[4];
  const float* bq = (const float*)d_in[5];
  const float* bk = (const float*)d_in[6];
  const float* bv = (const float*)d_in[7];
  const float* bo = (const float*)d_in[8];
  float* out = (float*)d_out;

  // Workspace: 64 MiB via lifetime overlap (all bf16 internals).
  uint8_t* ws = (uint8_t*)d_ws;
  const long MB16 = 16777216;
  __bf16* q_ws  = (__bf16*)(ws);
  __bf16* k_ws  = (__bf16*)(ws + 1 * MB16);
  __bf16* vT_ws = (__bf16*)(ws + 2 * MB16);
  __bf16* Wt    = (__bf16*)(ws + 3 * MB16);   // [3072][1024], 6 MiB
  __bf16* vout  = (__bf16*)(ws + 3 * MB16);   // [B,S,H,64], 16 MiB (after Wt dies)
  __bf16* WOt   = (__bf16*)(ws);              // [1024][1024], 2 MiB (after q_ws dies)

  dim3 tb(32, 8);
  // W_Q/K/V: per-head fp32 [1024 d][64 e] -> bf16 [64 e][1024 d], heads concat
  transpose_kernel<<<dim3(2, 32, 16), tb, 0, stream>>>(WQ, Wt,               1024, 64, 65536, 65536);
  transpose_kernel<<<dim3(2, 32, 16), tb, 0, stream>>>(WK, Wt + 1024 * 1024, 1024, 64, 65536, 65536);
  transpose_kernel<<<dim3(2, 32, 16), tb, 0, stream>>>(WV, Wt + 2048 * 1024, 1024, 64, 65536, 65536);

  // fused QKV projection: fp32 x [8192 x 1024] * bf16 Wt -> bf16 Q/K/V^T
  gemm_kernel<0><<<dim3(3072 / BN, 8192 / BM), 256, 0, stream>>>(
      x, Wt, BS_, 3072, DM_, bq, bk, bv, nullptr, q_ws, k_ws, vT_ws, nullptr);

  // flash attention (operand-swapped MFMA)
  attn_kernel<<<dim3(S_ / 128, H_, B_), 256, 0, stream>>>(q_ws, k_ws, vT_ws, vout);

  // W_O: fp32 [1024 he][1024 d] -> bf16 [1024 d][1024 he] (into dead q_ws)
  transpose_kernel<<<dim3(32, 32, 1), tb, 0, stream>>>(WO, WOt, 1024, 1024, 0, 0);

  // output projection: bf16 vout [8192 x 1024] * bf16 WOt -> fp32 out + b_O
  gemm_kernel<1><<<dim3(1024 / BN, 8192 / BM), 256, 0, stream>>>(
      vout, WOt, BS_, DM_, DM_, nullptr, nullptr, nullptr, bo, nullptr, nullptr, nullptr, out);
}

// Round 7
// 504.943 us; speedup vs baseline: 4.7694x; 1.0012x over previous
//
#include <hip/hip_runtime.h>
#include <hip/hip_bf16.h>
#include <cmath>

// Problem constants. I/O is FP32 (per reference); internals bf16.
#define B_ 4
#define S_ 2048
#define DM_ 1024
#define H_ 16
#define DH_ 64
#define BS_ (B_*S_)   // 8192 rows

typedef __bf16 bf16x8 __attribute__((ext_vector_type(8)));
typedef __bf16 bf16x4 __attribute__((ext_vector_type(4)));
typedef float  floatx4 __attribute__((ext_vector_type(4)));

// ---------------------------------------------------------------------------
// Batched 32x32 transpose: fp32 src[R][C] -> bf16 dst[C][R] (per batch)
// ---------------------------------------------------------------------------
__global__ void transpose_kernel(const float* __restrict__ src, __bf16* __restrict__ dst,
                                 int R, int C, long srcBatch, long dstBatch) {
  __shared__ __bf16 tile[32][33];
  int b = blockIdx.z;
  long sb = (long)b * srcBatch;
  dst += (long)b * dstBatch;
  int c0 = blockIdx.x * 32, r0 = blockIdx.y * 32;
  int tx = threadIdx.x, ty = threadIdx.y;      // block (32, 8)
  #pragma unroll
  for (int i = 0; i < 32; i += 8)
    tile[ty + i][tx] = (__bf16)src[sb + (long)(r0 + ty + i) * C + (c0 + tx)];
  __syncthreads();
  #pragma unroll
  for (int i = 0; i < 32; i += 8)
    dst[(long)(c0 + ty + i) * R + (r0 + tx)] = tile[tx][ty + i];
}

// ---------------------------------------------------------------------------
// Tiled MFMA GEMM: C[M][N] = A[M][K] * B[K][N], B supplied TRANSPOSED
// (bf16 Bt[N][K]). BM=BN=128, BK=64. 256 threads = 4 waves, wave = 64x64.
// EPI==0: A is FP32 (x), epilogue -> Q(*0.125*log2e)/K bf16 [B,H,S,64],
//         V bf16 TRANSPOSED [B,H,64,S]; fp32 biases
// EPI==1: A is bf16 (vout), epilogue -> fp32 out[M][N] + fp32 bias
// ---------------------------------------------------------------------------
#define BM 128
#define BN 128
#define BK 64
#define LDK 72   // padded LDS row stride (elements)

template<int EPI>
__global__ __launch_bounds__(256, 2) void gemm_kernel(
    const void* __restrict__ Avoid, const __bf16* __restrict__ Bt,
    int M, int N, int K,
    const float* __restrict__ bq, const float* __restrict__ bk,
    const float* __restrict__ bv, const float* __restrict__ bo,
    __bf16* __restrict__ q_ws, __bf16* __restrict__ k_ws,
    __bf16* __restrict__ vT_ws, float* __restrict__ out) {

  __shared__ __align__(16) __bf16 As[BM * LDK];
  __shared__ __align__(16) __bf16 Bs[BN * LDK];

  int tid  = threadIdx.x;
  int wave = tid >> 6, lane = tid & 63;
  int quad = lane >> 4, l15 = lane & 15;
  int wm = (wave >> 1) * 64, wn = (wave & 1) * 64;
  long m0 = (long)blockIdx.y * BM;
  long n0 = (long)blockIdx.x * BN;

  floatx4 acc[4][4] = {};   // [mt][nt]

  int arow  = tid >> 1;              // 0..127
  int ahalf = (tid & 1) * 32;        // element offset 0 or 32
  const float*  Af = (const float*) Avoid;   // EPI==0
  const __bf16* Ab = (const __bf16*)Avoid;   // EPI==1
  const __bf16* Bptr = Bt + (n0 + arow) * (long)K + ahalf;

  for (int k0 = 0; k0 < K; k0 += BK) {
    bf16x8 avb[4], bvv[4];
    if (EPI == 0) {
      const float* Ap = Af + (m0 + arow) * (long)K + ahalf + k0;
      #pragma unroll
      for (int c = 0; c < 4; c++) {
        float4 lo = *(const float4*)(Ap + c * 8);
        float4 hi = *(const float4*)(Ap + c * 8 + 4);
        bf16x8 t;
        t[0] = (__bf16)lo.x; t[1] = (__bf16)lo.y; t[2] = (__bf16)lo.z; t[3] = (__bf16)lo.w;
        t[4] = (__bf16)hi.x; t[5] = (__bf16)hi.y; t[6] = (__bf16)hi.z; t[7] = (__bf16)hi.w;
        avb[c] = t;
      }
    } else {
      const __bf16* Ap = Ab + (m0 + arow) * (long)K + ahalf + k0;
      #pragma unroll
      for (int c = 0; c < 4; c++) avb[c] = *(const bf16x8*)(Ap + c * 8);
    }
    #pragma unroll
    for (int c = 0; c < 4; c++) bvv[c] = *(const bf16x8*)(Bptr + k0 + c * 8);

    __syncthreads();   // WAR: previous iter's fragment reads done before overwrite
    #pragma unroll
    for (int c = 0; c < 4; c++) *(bf16x8*)(&As[arow * LDK + ahalf + c * 8]) = avb[c];
    #pragma unroll
    for (int c = 0; c < 4; c++) *(bf16x8*)(&Bs[arow * LDK + ahalf + c * 8]) = bvv[c];
    __syncthreads();

    #pragma unroll
    for (int kk = 0; kk < 2; kk++) {
      bf16x8 af[4], bff[4];
      #pragma unroll
      for (int mt = 0; mt < 4; mt++)
        af[mt] = *(const bf16x8*)(&As[(wm + mt * 16 + l15) * LDK + kk * 32 + quad * 8]);
      #pragma unroll
      for (int nt = 0; nt < 4; nt++)
        bff[nt] = *(const bf16x8*)(&Bs[(wn + nt * 16 + l15) * LDK + kk * 32 + quad * 8]);
      #pragma unroll
      for (int mt = 0; mt < 4; mt++)
        #pragma unroll
        for (int nt = 0; nt < 4; nt++)
          acc[mt][nt] = __builtin_amdgcn_mfma_f32_16x16x32_bf16(af[mt], bff[nt], acc[mt][nt], 0, 0, 0);
    }
  }

  if (EPI == 0) {
    // n in [0,3072): seg 0=Q,1=K,2=V ; h=(n&1023)>>6 ; e=n&63
    #pragma unroll
    for (int nt = 0; nt < 4; nt++) {
      long n = n0 + wn + nt * 16 + l15;
      int seg = (int)(n >> 10);
      int he  = (int)(n & 1023);
      int h = he >> 6, e = he & 63;
      const float* bias = (seg == 0 ? bq : (seg == 1 ? bk : bv));
      float bval = bias[he];
      // Q scale folds 1/sqrt(64) AND log2(e): scores arrive in log2 units
      float scale = (seg == 0 ? 0.125f * 1.44269504088896340f : 1.0f);
      #pragma unroll
      for (int mt = 0; mt < 4; mt++) {
        #pragma unroll
        for (int r = 0; r < 4; r++) {
          long m = m0 + wm + mt * 16 + quad * 4 + r;
          int b = (int)(m >> 11), s = (int)(m & 2047);
          float v = (acc[mt][nt][r] + bval) * scale;
          if (seg == 0)
            q_ws[((long)(b * 16 + h) * 2048 + s) * 64 + e] = (__bf16)v;
          else if (seg == 1)
            k_ws[((long)(b * 16 + h) * 2048 + s) * 64 + e] = (__bf16)v;
          else   // V transposed: [B,H,64,S]
            vT_ws[((long)(b * 16 + h) * 64 + e) * 2048 + s] = (__bf16)v;
        }
      }
    }
  } else {
    #pragma unroll
    for (int mt = 0; mt < 4; mt++) {
      #pragma unroll
      for (int r = 0; r < 4; r++) {
        long m = m0 + wm + mt * 16 + quad * 4 + r;
        #pragma unroll
        for (int nt = 0; nt < 4; nt++) {
          long n = n0 + wn + nt * 16 + l15;
          out[m * N + n] = acc[mt][nt][r] + bo[n];
        }
      }
    }
  }
}

// ---------------------------------------------------------------------------
// Flash attention, operand-swapped (S^T / O^T). 1D grid, 1024 blocks, XCD-
// swizzled: all 16 q-tiles of one (b,h) share id%8 -> same XCD L2 holds that
// (b,h)'s K+V (0.5 MB). Block = 4 waves; wave owns 32 q-rows. No barriers
// (P is wave-private). Scores arrive in log2 units (Q pre-scaled).
//   QK^T: mfma(kf, qf) -> Sc^T[key][q], col=q=lane&15.
//   softmax: per-lane state; only the row-max needs cross-quad shuffles;
//            l-sum kept as per-lane partial, reduced once after the loop.
//   exp2 via __builtin_amdgcn_exp2f (single v_exp_f32 - no libcall).
//   PV:   mfma(vf, pf) -> O^T[d][q]; V loads hoisted to iter top.
// Q,K: [B,H,S,64] bf16; Vt: [B,H,64,S] bf16. Writes vout [B,S,H,64] bf16.
// ---------------------------------------------------------------------------
#define LDP 72   // P row stride (elems): 144 B, 16B-aligned

__global__ __launch_bounds__(256, 2) void attn_kernel(
    const __bf16* __restrict__ Q, const __bf16* __restrict__ Kk,
    const __bf16* __restrict__ Vt, __bf16* __restrict__ vout) {

  __shared__ __align__(16) __bf16 Plds[4][2][16 * LDP];

  int tid = threadIdx.x, wave = tid >> 6, lane = tid & 63;
  int quad = lane >> 4, l15 = lane & 15;

  // XCD swizzle decode: id = xcd + 8*(qt + 16*bhhi); bh = bhhi*8 + xcd
  int id = blockIdx.x;
  int xcd = id & 7, rest = id >> 3;
  int qt = rest & 15, bhhi = rest >> 4;
  int bh = bhhi * 8 + xcd;
  int b = bh >> 4, h = bh & 15;
  int q0 = qt * 128 + wave * 32;

  const __bf16* Qbh = Q  + (long)(b * 16 + h) * 2048 * 64;
  const __bf16* Kbh = Kk + (long)(b * 16 + h) * 2048 * 64;
  const __bf16* Vbh = Vt + (long)(b * 16 + h) * 64 * 2048;

  // Q fragments (B-operand): lane holds Q[q0+qh*16+l15][quad*8+j (+32)]
  bf16x8 qf[2][2];
  #pragma unroll
  for (int qh = 0; qh < 2; qh++)
    #pragma unroll
    for (int t = 0; t < 2; t++)
      qf[qh][t] = *(const bf16x8*)(Qbh + (long)(q0 + qh * 16 + l15) * 64 + t * 32 + quad * 8);

  floatx4 o[2][4] = {};           // O^T frags: [qh][dn]; row=d, col=q=l15
  float mrow[2] = { -1e30f, -1e30f };
  float lpart[2] = { 0.f, 0.f };  // per-lane PARTIAL sum (this quad's 16 keys/iter)

  for (int kb = 0; kb < 2048; kb += 64) {
    // ---- issue ALL global loads for this iter up front ----
    bf16x8 kf[4][2];
    #pragma unroll
    for (int nt = 0; nt < 4; nt++) {
      const __bf16* kp = Kbh + (long)(kb + nt * 16 + l15) * 64 + quad * 8;
      kf[nt][0] = *(const bf16x8*)kp;
      kf[nt][1] = *(const bf16x8*)(kp + 32);
    }
    bf16x8 vf[2][4];
    #pragma unroll
    for (int t = 0; t < 2; t++)
      #pragma unroll
      for (int dn = 0; dn < 4; dn++)
        vf[t][dn] = *(const bf16x8*)(Vbh + (long)(dn * 16 + l15) * 2048 + kb + t * 32 + quad * 8);

    // ---- Sc^T[key][q] in log2 units ----
    floatx4 sc[2][4];
    #pragma unroll
    for (int nt = 0; nt < 4; nt++) {
      #pragma unroll
      for (int qh = 0; qh < 2; qh++) {
        floatx4 z = { 0.f, 0.f, 0.f, 0.f };
        z = __builtin_amdgcn_mfma_f32_16x16x32_bf16(kf[nt][0], qf[qh][0], z, 0, 0, 0);
        sc[qh][nt] = __builtin_amdgcn_mfma_f32_16x16x32_bf16(kf[nt][1], qf[qh][1], z, 0, 0, 0);
      }
    }

    // ---- online softmax (per-lane; only max crosses quads) ----
    #pragma unroll
    for (int qh = 0; qh < 2; qh++) {
      float tm = sc[qh][0][0];
      #pragma unroll
      for (int nt = 0; nt < 4; nt++)
        #pragma unroll
        for (int r = 0; r < 4; r++) tm = fmaxf(tm, sc[qh][nt][r]);
      tm = fmaxf(tm, __shfl_xor(tm, 16, 64));
      tm = fmaxf(tm, __shfl_xor(tm, 32, 64));
      float mnew = fmaxf(mrow[qh], tm);
      float alpha = __builtin_amdgcn_exp2f(mrow[qh] - mnew);
      mrow[qh] = mnew;

      __bf16* Pq = &Plds[wave][qh][0];
      float rs = 0.f;
      #pragma unroll
      for (int nt = 0; nt < 4; nt++) {
        bf16x4 pw;
        #pragma unroll
        for (int r = 0; r < 4; r++) {
          float p = __builtin_amdgcn_exp2f(sc[qh][nt][r] - mnew);
          rs += p;
          pw[r] = (__bf16)p;
        }
        *(bf16x4*)(&Pq[l15 * LDP + nt * 16 + quad * 4]) = pw;   // P[q][key], 4 keys
      }
      lpart[qh] = alpha * lpart[qh] + rs;       // partial: this quad's keys only
      #pragma unroll
      for (int dn = 0; dn < 4; dn++) o[qh][dn] *= alpha;   // alpha uniform across quads
    }

    // ---- O^T += V^T x P^T ----
    #pragma unroll
    for (int t = 0; t < 2; t++) {
      bf16x8 pf0 = *(const bf16x8*)(&Plds[wave][0][l15 * LDP + t * 32 + quad * 8]);
      bf16x8 pf1 = *(const bf16x8*)(&Plds[wave][1][l15 * LDP + t * 32 + quad * 8]);
      #pragma unroll
      for (int dn = 0; dn < 4; dn++) {
        o[0][dn] = __builtin_amdgcn_mfma_f32_16x16x32_bf16(vf[t][dn], pf0, o[0][dn], 0, 0, 0);
        o[1][dn] = __builtin_amdgcn_mfma_f32_16x16x32_bf16(vf[t][dn], pf1, o[1][dn], 0, 0, 0);
      }
    }
  }

  // final cross-quad l reduction + write O^T -> vout [B,S,H,64]
  #pragma unroll
  for (int qh = 0; qh < 2; qh++) {
    float l = lpart[qh];
    l += __shfl_xor(l, 16, 64);
    l += __shfl_xor(l, 32, 64);
    float rl = 1.f / l;
    int s = q0 + qh * 16 + l15;
    __bf16* outr = vout + ((long)(b * 2048 + s) * 16 + h) * 64;
    #pragma unroll
    for (int dn = 0; dn < 4; dn++) {
      bf16x4 w;
      #pragma unroll
      for (int r = 0; r < 4; r++) w[r] = (__bf16)(o[qh][dn][r] * rl);
      *(bf16x4*)(outr + dn * 16 + quad * 4) = w;
    }
  }
}

// ---------------------------------------------------------------------------
extern "C" void kernel_launch(void* const* d_in, const int* in_sizes, int n_in,
                              void* d_out, int out_size, void* d_ws, size_t ws_size,
                              hipStream_t stream) {
  const float* x  = (const float*)d_in[0];
  const float* WQ = (const float*)d_in[1];
  const float* WK = (const float*)d_in[2];
  const float* WV = (const float*)d_in[3];
  const float* WO = (const float*)d_in[4];
  const float* bq = (const float*)d_in[5];
  const float* bk = (const float*)d_in[6];
  const float* bv = (const float*)d_in[7];
  const float* bo = (const float*)d_in[8];
  float* out = (float*)d_out;

  // Workspace: 64 MiB via lifetime overlap (all bf16 internals).
  uint8_t* ws = (uint8_t*)d_ws;
  const long MB16 = 16777216;
  __bf16* q_ws  = (__bf16*)(ws);
  __bf16* k_ws  = (__bf16*)(ws + 1 * MB16);
  __bf16* vT_ws = (__bf16*)(ws + 2 * MB16);
  __bf16* Wt    = (__bf16*)(ws + 3 * MB16);   // [3072][1024], 6 MiB
  __bf16* vout  = (__bf16*)(ws + 3 * MB16);   // [B,S,H,64], 16 MiB (after Wt dies)
  __bf16* WOt   = (__bf16*)(ws);              // [1024][1024], 2 MiB (after q_ws dies)

  dim3 tb(32, 8);
  // W_Q/K/V: per-head fp32 [1024 d][64 e] -> bf16 [64 e][1024 d], heads concat
  transpose_kernel<<<dim3(2, 32, 16), tb, 0, stream>>>(WQ, Wt,               1024, 64, 65536, 65536);
  transpose_kernel<<<dim3(2, 32, 16), tb, 0, stream>>>(WK, Wt + 1024 * 1024, 1024, 64, 65536, 65536);
  transpose_kernel<<<dim3(2, 32, 16), tb, 0, stream>>>(WV, Wt + 2048 * 1024, 1024, 64, 65536, 65536);

  // fused QKV projection: fp32 x [8192 x 1024] * bf16 Wt -> bf16 Q/K/V^T
  gemm_kernel<0><<<dim3(3072 / BN, 8192 / BM), 256, 0, stream>>>(
      x, Wt, BS_, 3072, DM_, bq, bk, bv, nullptr, q_ws, k_ws, vT_ws, nullptr);

  // flash attention (operand-swapped MFMA, XCD-swizzled 1D grid)
  attn_kernel<<<dim3(1024), 256, 0, stream>>>(q_ws, k_ws, vT_ws, vout);

  // W_O: fp32 [1024 he][1024 d] -> bf16 [1024 d][1024 he] (into dead q_ws)
  transpose_kernel<<<dim3(32, 32, 1), tb, 0, stream>>>(WO, WOt, 1024, 1024, 0, 0);

  // output projection: bf16 vout [8192 x 1024] * bf16 WOt -> fp32 out + b_O
  gemm_kernel<1><<<dim3(1024 / BN, 8192 / BM), 256, 0, stream>>>(
      vout, WOt, BS_, DM_, DM_, nullptr, nullptr, nullptr, bo, nullptr, nullptr, nullptr, out);
}